// Round 5
// baseline (362.159 us; speedup 1.0000x reference)
//
#include <hip/hip_runtime.h>
#include <cstdint>
#include <cstddef>

// ---------- bf16 helpers (bit-level) ----------
__device__ __forceinline__ uint16_t f2bf(float f) {
    union { float f; uint32_t i; } w; w.f = f;
    uint32_t x = w.i;
    uint32_t r = (x + 0x7FFFu + ((x >> 16) & 1u)) >> 16;   // RNE
    return (uint16_t)r;
}

typedef __bf16 bf16x8 __attribute__((ext_vector_type(8)));
typedef float  f32x4  __attribute__((ext_vector_type(4)));

// async global->LDS, 16B per lane; LDS dest is wave-uniform base + lane*16
__device__ __forceinline__ void load_lds16(const void* gptr, void* lptr) {
    __builtin_amdgcn_global_load_lds(
        (__attribute__((address_space(1))) void*)gptr,
        (__attribute__((address_space(3))) void*)lptr,
        16, 0, 0);
}

// ---------- 256xBN phased GEMM engine (frozen at R2 form) ----------
// C[M,N] = act(A[M,K] @ BT[N,K]^T + bias); A,BT bf16; BK=64 as 2 kh-subtiles.
// ENGINE STATUS (R0-R3 post-mortems): runs at ~570-600 TF. Schedule micro-
// fixes (lgkmcnt pin R2, sched_barrier pins R3: -7.7us, reverted) do not move
// it — consistent with learn_hip m232 (8-phase port null at 539-567 TF,
// "needs derived-waits port"). Frozen here; algebra/traffic wins this round.
// Grid is ALWAYS 256 blocks (1/CU): mtiles * nbx == 256, nbx = 1<<nbxShift.
// XCD swizzle: q = (g&7)*32 + (g>>3); by = q>>nbxShift (M-tile), bx = rest.
// Batch on B only: bz = by >> byShift.
template<int BN, int OUTFP32, int RELU, int ROWBIAS>
__global__ __launch_bounds__(512, 2)
void gemm256(const uint16_t* __restrict__ A, const uint16_t* __restrict__ BT,
             const float* __restrict__ bias, void* __restrict__ Cv,
             int K, int lda, int ldb, int ldc,
             long long sB, int byShift, int nbxShift)
{
    extern __shared__ uint16_t lds[];
    constexpr int SB  = (BN == 256) ? 2 : 1;  // B gload_lds insts per kh
    constexpr int WN  = BN / 64;              // waves along N (4 or 2)
    constexpr int MI  = 2 * WN;               // frag-rows per wave (8 or 4)
    constexpr int SBE = BN * 32;              // B subtile elems

    const int g   = (int)blockIdx.x + (int)gridDim.x * (int)blockIdx.y;
    const int xcd = g & 7, ii = g >> 3;
    const int q   = xcd * 32 + ii;            // 0..255
    const int by  = q >> nbxShift;
    const int bx  = q & ((1 << nbxShift) - 1);
    const int gm0 = by * 256, gn0 = bx * BN;
    const int bz  = by >> byShift;
    BT += (long long)bz * sB;

    const int t    = threadIdx.x;
    const int w    = t >> 6, lane = t & 63;
    const int l15  = lane & 15, quad = lane >> 4;
    const int wr   = w / WN, wc = w % WN;

    // frag-read swizzle + row bases
    const int cpr  = quad ^ ((l15 >> 1) & 3);
    const int arow = wr * (32 * WN) + l15;    // + (mh*64) + i*16
    const int brow = wc * 64 + l15;           // + ni*16

    // staging map: thread t covers row r0 = t>>2 (0..127), 16B chunk qg of that
    // row, where qg = (t&3) ^ ((r0>>1)&3).
    const int r0 = t >> 2;
    const int qg = (t & 3) ^ ((t >> 3) & 3);
    const uint16_t* aS0 = A  + (size_t)(gm0 + r0) * lda + qg * 8;
    const uint16_t* aS1 = aS0 + (size_t)128 * lda;
    const uint16_t* bS0 = BT + (size_t)(gn0 + r0) * ldb + qg * 8;
    const uint16_t* bS1 = bS0 + (size_t)128 * ldb;   // deref'd only if BN==256
    const int ldw = w * 512;                  // per-wave LDS elem offset

#define SUBA(nb, kh) (lds + ((nb) * 2 + (kh)) * 8192)
#define SUBB(nb, kh) (lds + 32768 + ((nb) * 2 + (kh)) * SBE)
#define STAGE_A(nb, kh, k0s) do {                                               \
        load_lds16(aS0 + (k0s) + (kh) * 32, (void*)(SUBA(nb, kh) + ldw));       \
        load_lds16(aS1 + (k0s) + (kh) * 32, (void*)(SUBA(nb, kh) + 4096 + ldw));\
    } while (0)
#define STAGE_B(nb, kh, k0s) do {                                               \
        load_lds16(bS0 + (k0s) + (kh) * 32, (void*)(SUBB(nb, kh) + ldw));       \
        if constexpr (BN == 256)                                                \
            load_lds16(bS1 + (k0s) + (kh) * 32,                                 \
                       (void*)(SUBB(nb, kh) + 4096 + ldw));                     \
    } while (0)
#define VMW do {                                                                \
        if constexpr (SB == 2) asm volatile("s_waitcnt vmcnt(4)" ::: "memory"); \
        else                   asm volatile("s_waitcnt vmcnt(3)" ::: "memory"); \
    } while (0)
#define LGKM0 asm volatile("s_waitcnt lgkmcnt(0)" ::: "memory")
#define NOWAIT ((void)0)

    f32x4 acc[MI][4] = {};
    bf16x8 bF[4];

    // prologue: stage tile 0 fully; wait until (Ak0,Bk0) landed
    STAGE_A(0, 0, 0); STAGE_B(0, 0, 0); STAGE_A(0, 1, 0); STAGE_B(0, 1, 0);
    VMW;
    __builtin_amdgcn_s_barrier();

    const int NT = K >> 6;
    for (int kt = 0; kt < NT; ++kt) {
        const int buf = kt & 1, nb = buf ^ 1;
        const int nk0 = (kt + 1 < NT) ? ((kt + 1) << 6) : 0;   // wrap: dead stage

        if constexpr (BN == 256) {
#define PHASE256(kh, mh, STAGE_STMT, VM_STMT)                                       \
            {                                                                       \
                const uint16_t* As_ = SUBA(buf, kh);                                \
                const uint16_t* Bs_ = SUBB(buf, kh);                                \
                bf16x8 aF[4];                                                       \
                _Pragma("unroll")                                                   \
                for (int i = 0; i < 4; i++)                                         \
                    aF[i] = *(const bf16x8*)(As_ + (arow + (mh) * 64 + i * 16) * 32 + cpr * 8); \
                if ((mh) == 0) {                                                    \
                    _Pragma("unroll")                                               \
                    for (int ni = 0; ni < 4; ni++)                                  \
                        bF[ni] = *(const bf16x8*)(Bs_ + (brow + ni * 16) * 32 + cpr * 8); \
                }                                                                   \
                STAGE_STMT;                                                         \
                __builtin_amdgcn_s_barrier();                                       \
                LGKM0;                                                              \
                __builtin_amdgcn_s_setprio(1);                                      \
                _Pragma("unroll")                                                   \
                for (int i = 0; i < 4; i++)                                         \
                    _Pragma("unroll")                                               \
                    for (int ni = 0; ni < 4; ni++)                                  \
                        acc[(mh) * 4 + i][ni] = __builtin_amdgcn_mfma_f32_16x16x32_bf16( \
                            aF[i], bF[ni], acc[(mh) * 4 + i][ni], 0, 0, 0);         \
                __builtin_amdgcn_s_setprio(0);                                      \
                VM_STMT;                                                            \
                __builtin_amdgcn_s_barrier();                                       \
            }
            PHASE256(0, 0, STAGE_A(nb, 0, nk0), NOWAIT)
            PHASE256(0, 1, STAGE_B(nb, 0, nk0), VMW)
            PHASE256(1, 0, STAGE_A(nb, 1, nk0), NOWAIT)
            PHASE256(1, 1, STAGE_B(nb, 1, nk0), VMW)
#undef PHASE256
        } else {
#define PHASE128(kh)                                                                \
            {                                                                       \
                const uint16_t* As_ = SUBA(buf, kh);                                \
                const uint16_t* Bs_ = SUBB(buf, kh);                                \
                bf16x8 aF[4], bG[4];                                                \
                _Pragma("unroll")                                                   \
                for (int i = 0; i < 4; i++)                                         \
                    aF[i] = *(const bf16x8*)(As_ + (arow + i * 16) * 32 + cpr * 8); \
                _Pragma("unroll")                                                   \
                for (int ni = 0; ni < 4; ni++)                                      \
                    bG[ni] = *(const bf16x8*)(Bs_ + (brow + ni * 16) * 32 + cpr * 8); \
                STAGE_A(nb, kh, nk0);                                               \
                STAGE_B(nb, kh, nk0);                                               \
                __builtin_amdgcn_s_barrier();                                       \
                LGKM0;                                                              \
                __builtin_amdgcn_s_setprio(1);                                      \
                _Pragma("unroll")                                                   \
                for (int i = 0; i < 4; i++)                                         \
                    _Pragma("unroll")                                               \
                    for (int ni = 0; ni < 4; ni++)                                  \
                        acc[i][ni] = __builtin_amdgcn_mfma_f32_16x16x32_bf16(       \
                            aF[i], bG[ni], acc[i][ni], 0, 0, 0);                    \
                __builtin_amdgcn_s_setprio(0);                                      \
                VMW;                                                                \
                __builtin_amdgcn_s_barrier();                                       \
            }
            PHASE128(0)
            PHASE128(1)
#undef PHASE128
        }
    }
    asm volatile("s_waitcnt vmcnt(0)" ::: "memory");   // drain dead stage

    // epilogue: C/D layout col=lane&15, row=quad*4+reg
#pragma unroll
    for (int ni = 0; ni < 4; ni++) {
        const int gcol = gn0 + wc * 64 + ni * 16 + l15;
        const float bv = (!ROWBIAS && bias) ? bias[gcol] : 0.0f;
#pragma unroll
        for (int mi = 0; mi < MI; mi++) {
#pragma unroll
            for (int r = 0; r < 4; r++) {
                const int grow = gm0 + wr * (32 * WN) + mi * 16 + quad * 4 + r;
                float v = acc[mi][ni][r] + (ROWBIAS ? bias[grow] : bv);
                if (RELU) v = fmaxf(v, 0.0f);
                if (OUTFP32) ((float*)Cv)[(size_t)grow * ldc + gcol] = v;
                else         ((uint16_t*)Cv)[(size_t)grow * ldc + gcol] = f2bf(v);
            }
        }
    }
#undef SUBA
#undef SUBB
#undef STAGE_A
#undef STAGE_B
#undef VMW
#undef LGKM0
#undef NOWAIT
}

// ---------- legacy 128x128 GEMM (for the small GT = (W2k@D2L)^T) ----------
template<int AFP32, int OUTFP32, int RELU>
__global__ __launch_bounds__(256, 3)
void gemm_bt(const void* __restrict__ Av, const uint16_t* __restrict__ BT,
             const float* __restrict__ bias, void* __restrict__ Cv,
             int K, int lda, int ldb, int ldc,
             long long sA, long long sB, long long sC)
{
    __shared__ uint16_t As[128 * 32];
    __shared__ uint16_t Bs[128 * 32];

    const int nx = (int)gridDim.x, ny = (int)gridDim.y, nz = (int)gridDim.z;
    const int g   = (int)blockIdx.x + nx * ((int)blockIdx.y + ny * (int)blockIdx.z);
    const int xcd = g & 7;
    const int ii  = g >> 3;
    const int xz  = 8 / nz;
    const int bz  = xcd / xz;
    const int sub = xcd % xz;
    const int ypc = ny / xz;
    const int by  = sub * ypc + ii % ypc;
    const int bx  = ii / ypc;

    const int t    = threadIdx.x;
    const int lane = t & 63;
    const int w    = t >> 6;
    const int quad = lane >> 4;
    const int l15  = lane & 15;
    const int wr   = w >> 1;
    const int wc   = w & 1;
    const int gm0  = by * 128;
    const int gn0  = bx * 128;

    BT += (long long)bz * sB;

    f32x4 acc[4][4] = {};

    const int ch_r = lane >> 2;
    const int ch_c = (lane & 3) * 8;

    for (int k0 = 0; k0 < K; k0 += 32) {
        __syncthreads();
        {
            int row = w * 16 + ch_r;
            load_lds16(BT + (size_t)(gn0 + row) * ldb + k0 + ch_c, (void*)(Bs + w * 512));
            load_lds16(BT + (size_t)(gn0 + row + 64) * ldb + k0 + ch_c, (void*)(Bs + (w + 4) * 512));
        }
        {
            const uint16_t* A = (const uint16_t*)Av + (long long)bz * sA;
            int row = w * 16 + ch_r;
            load_lds16(A + (size_t)(gm0 + row) * lda + k0 + ch_c, (void*)(As + w * 512));
            load_lds16(A + (size_t)(gm0 + row + 64) * lda + k0 + ch_c, (void*)(As + (w + 4) * 512));
        }
        __syncthreads();

        bf16x8 af[4], bfr[4];
#pragma unroll
        for (int i = 0; i < 4; i++) {
            af[i]  = *(const bf16x8*)(As + (wr * 64 + i * 16 + l15) * 32 + quad * 8);
            bfr[i] = *(const bf16x8*)(Bs + (wc * 64 + i * 16 + l15) * 32 + quad * 8);
        }
#pragma unroll
        for (int mi = 0; mi < 4; mi++)
#pragma unroll
            for (int ni = 0; ni < 4; ni++)
                acc[mi][ni] = __builtin_amdgcn_mfma_f32_16x16x32_bf16(af[mi], bfr[ni], acc[mi][ni], 0, 0, 0);
    }

#pragma unroll
    for (int ni = 0; ni < 4; ni++) {
        const int gcol = gn0 + wc * 64 + ni * 16 + l15;
        const float bv = bias ? bias[gcol] : 0.0f;
#pragma unroll
        for (int mi = 0; mi < 4; mi++) {
#pragma unroll
            for (int r = 0; r < 4; r++) {
                const int grow = gm0 + wr * 64 + mi * 16 + quad * 4 + r;
                float v = acc[mi][ni][r] + bv;
                if (RELU) v = fmaxf(v, 0.0f);
                if (OUTFP32) {
                    float* C = (float*)Cv + (long long)bz * sC;
                    C[(size_t)grow * ldc + gcol] = v;
                } else {
                    uint16_t* C = (uint16_t*)Cv + (long long)bz * sC;
                    C[(size_t)grow * ldc + gcol] = f2bf(v);
                }
            }
        }
    }
}

// ---------- elementwise cast fp32 -> bf16 (8 elems/thread) ----------
__global__ __launch_bounds__(256)
void cast_f32_bf16(const float* __restrict__ src, uint16_t* __restrict__ dst)
{
    const size_t i = ((size_t)blockIdx.x * 256 + threadIdx.x) * 8;
    float4 a = *(const float4*)(src + i);
    float4 b = *(const float4*)(src + i + 4);
    union { __bf16 h[8]; uint4 q; } u;
    u.h[0] = (__bf16)a.x; u.h[1] = (__bf16)a.y;
    u.h[2] = (__bf16)a.z; u.h[3] = (__bf16)a.w;
    u.h[4] = (__bf16)b.x; u.h[5] = (__bf16)b.y;
    u.h[6] = (__bf16)b.z; u.h[7] = (__bf16)b.w;
    *(uint4*)(dst + i) = u.q;
}

// ---------- transpose fp32 -> bf16: dst[n][k] = bf16(src[k][n]) ----------
__global__ __launch_bounds__(256)
void transpose_f32_to_bf16(const float* __restrict__ src, uint16_t* __restrict__ dst,
                           int src_ld, int dst_ld)
{
    __shared__ uint16_t tile[64 * 65];
    const int k0 = blockIdx.y * 64, n0 = blockIdx.x * 64;
    const int t = threadIdx.x;
#pragma unroll
    for (int i = 0; i < 16; i++) {
        int idx = i * 256 + t;
        int r = idx >> 6, c = idx & 63;
        tile[c * 65 + r] = f2bf(src[(size_t)(k0 + r) * src_ld + n0 + c]);
    }
    __syncthreads();
#pragma unroll
    for (int i = 0; i < 16; i++) {
        int idx = i * 256 + t;
        int n = idx >> 6, k = idx & 63;
        dst[(size_t)(n0 + n) * dst_ld + k0 + k] = tile[n * 65 + k];
    }
}

// ---------- gb[n] = sum_dd b2k[dd] * D2L[dd][n]  (n < 2048) ----------
__global__ __launch_bounds__(256)
void score_bias(const float* __restrict__ b2, const float* __restrict__ D2L,
                float* __restrict__ gb)
{
    const int n = blockIdx.x * 256 + threadIdx.x;
    float s = 0.f;
    for (int dd = 0; dd < 1024; ++dd)
        s += b2[dd] * D2L[(size_t)dd * 4096 + n];
    gb[n] = s;
}

// ---------- in-place masked softmax, fp32; also emits bf16 copy ----------
__global__ __launch_bounds__(256)
void softmax_rows_f32(float* __restrict__ S, uint16_t* __restrict__ Sbf,
                      const int* __restrict__ mask, int L)
{
    const int row = blockIdx.x;
    const int b = row >> 11;                 // L == 2048
    float* rp = S + (size_t)row * L;
    uint16_t* bp = Sbf + (size_t)row * L;
    const int* mrow = mask + (size_t)b * L;
    const int t = threadIdx.x;
    const int c0 = t * 8;

    float v[8];
    *(float4*)(v + 0) = *(const float4*)(rp + c0);
    *(float4*)(v + 4) = *(const float4*)(rp + c0 + 4);
    bool mk[8];
    float lmax = -1e30f;
#pragma unroll
    for (int j = 0; j < 8; j++) {
        mk[j] = (mrow[c0 + j] != 0);
        if (mk[j]) lmax = fmaxf(lmax, v[j]);
    }
#pragma unroll
    for (int off = 32; off > 0; off >>= 1)
        lmax = fmaxf(lmax, __shfl_xor(lmax, off, 64));

    __shared__ float redm[4];
    __shared__ float reds[4];
    const int w = t >> 6, lane = t & 63;
    if (lane == 0) redm[w] = lmax;
    __syncthreads();
    lmax = fmaxf(fmaxf(redm[0], redm[1]), fmaxf(redm[2], redm[3]));

    float e[8];
    float lsum = 0.f;
#pragma unroll
    for (int j = 0; j < 8; j++) {
        e[j] = mk[j] ? __expf(v[j] - lmax) : 0.0f;
        lsum += e[j];
    }
#pragma unroll
    for (int off = 32; off > 0; off >>= 1)
        lsum += __shfl_xor(lsum, off, 64);
    if (lane == 0) reds[w] = lsum;
    __syncthreads();
    lsum = reds[0] + reds[1] + reds[2] + reds[3];

    const float inv = 1.0f / lsum;
    uint16_t ub[8];
#pragma unroll
    for (int j = 0; j < 8; j++) {
        v[j] = e[j] * inv;
        ub[j] = f2bf(v[j]);
    }
    *(float4*)(rp + c0)     = *(const float4*)(v + 0);
    *(float4*)(rp + c0 + 4) = *(const float4*)(v + 4);
    *(uint4*)(bp + c0)      = *(const uint4*)ub;
}

extern "C" void kernel_launch(void* const* d_in, const int* in_sizes, int n_in,
                              void* d_out, int out_size, void* d_ws, size_t ws_size,
                              hipStream_t stream)
{
    const float* x    = (const float*)d_in[0];  // [4,2048,1024] fp32
    const int*   mask = (const int*)d_in[1];    // [4,1,2048] int32
    const float* W1   = (const float*)d_in[2];  // [1024,1024]
    const float* b1   = (const float*)d_in[3];  // [1024]
    const float* W2   = (const float*)d_in[4];  // [1024,2048]
    const float* b2   = (const float*)d_in[5];  // [2048]
    const float* D2L  = (const float*)d_in[6];  // [1024,4096]

    const int Lr = 2048, D = 1024, M = 4 * Lr;  // M = 8192
    float* outp = (float*)d_out;                // [8192][1024] fp32
    float* attn = outp + (size_t)M * D;         // [8192][2048] fp32

    // ws layout (bf16 elems), 37M elems = 74MB, time-multiplexed:
    //  @0    W1T   1M   (dead after h GEMM; gbuf reuses this region AFTER it)
    //  @1M   W2T   2M   ([2048][1024] = W2^T; rows 1024.. = W2v^T)
    //  @3M   D2LT  2M   (D2L[:, :2048]^T)
    //  @5M   hbuf  8M   (h)
    //  @13M  vT    8M   ([1024][8192] bf16, batch b = cols b*2048..)
    //  @21M  W2bf  2M early (W2 cast)  ->  abf 16M late (bf16 attn, 21M..37M)
    //  @29M  xbf   8M early (x cast; dead after h GEMM)  ->  GT 2M late
    // Timeline audit (R4 post-mortem): gbuf formerly sat at @31M INSIDE xbf and
    // score_bias ran before the h GEMM consumed xbf -> corrupted h rows 2048+.
    // Now: gbuf=@0 (W1T region) and score_bias launches AFTER the h GEMM.
    uint16_t* W1T  = (uint16_t*)d_ws;
    uint16_t* W2T  = W1T + (size_t)1024 * 1024;
    uint16_t* D2LT = W2T + (size_t)2048 * 1024;
    uint16_t* hbuf = D2LT + (size_t)2048 * 1024;
    uint16_t* vT   = hbuf + (size_t)M * D;
    uint16_t* reg2 = vT + (size_t)1024 * 8192;      // @21M
    uint16_t* W2bf = reg2;
    uint16_t* abf  = reg2;
    uint16_t* reg3 = reg2 + (size_t)M * 2048;       // @29M
    uint16_t* xbf  = reg3;
    uint16_t* GT   = reg3;
    float*    gbuf = (float*)W1T;                   // @0, written after h GEMM

    dim3 blk(256);
    const dim3 g256(8, 32), b512(512);

    // opt-in dynamic LDS (host-side attr set; graph-capture-safe)
    hipFuncSetAttribute(reinterpret_cast<const void*>(&gemm256<128, 0, 1, 0>),
                        hipFuncAttributeMaxDynamicSharedMemorySize, 98304);
    hipFuncSetAttribute(reinterpret_cast<const void*>(&gemm256<128, 0, 0, 1>),
                        hipFuncAttributeMaxDynamicSharedMemorySize, 98304);
    hipFuncSetAttribute(reinterpret_cast<const void*>(&gemm256<256, 1, 0, 0>),
                        hipFuncAttributeMaxDynamicSharedMemorySize, 131072);
    hipFuncSetAttribute(reinterpret_cast<const void*>(&gemm256<128, 1, 0, 0>),
                        hipFuncAttributeMaxDynamicSharedMemorySize, 98304);

    // casts / transposes of inputs
    cast_f32_bf16<<<dim3(4096), blk, 0, stream>>>(x, xbf);
    cast_f32_bf16<<<dim3(1024), blk, 0, stream>>>(W2, W2bf);     // [1024][2048]
    transpose_f32_to_bf16<<<dim3(16, 16), blk, 0, stream>>>(W1,  W1T,  1024, 1024);
    transpose_f32_to_bf16<<<dim3(32, 16), blk, 0, stream>>>(W2,  W2T,  2048, 1024);
    transpose_f32_to_bf16<<<dim3(32, 16), blk, 0, stream>>>(D2L, D2LT, 4096, 1024);

    // h = relu(x @ W1 + b1)   [8192,1024] K=1024  (BN=128, mt=32, nbx=8)
    gemm256<128, 0, 1, 0><<<g256, b512, 98304, stream>>>(xbf, W1T, b1, hbuf,
        1024, 1024, 1024, 1024, 0, 30, 3);

    // gb = b2k @ D2L[:, :2048]   (AFTER h GEMM: W1T region is dead now)
    score_bias<<<dim3(8), blk, 0, stream>>>(b2, D2L, gbuf);

    // GT = (W2k @ D2L[:, :2048])^T  [2048,1024] bf16:
    //   GT[n][c] = sum_d D2LT[n][d] * W2bf[c][d]   (legacy engine, 128 blocks)
    //   xbf region is dead after h GEMM; GT reuses it.
    gemm_bt<0, 0, 0><<<dim3(8, 16, 1), blk, 0, stream>>>(D2LT, W2bf, nullptr, GT,
        1024, 1024, 2048, 1024, 0, 0, 0);

    // vT = W2v^T @ h^T + b2v (row-bias)  -> [1024][8192] bf16
    //   A = W2T rows 1024.., BT = h  (BN=128, mt=4, nbx=64)
    gemm256<128, 0, 0, 1><<<g256, b512, 98304, stream>>>(W2T + (size_t)1024 * 1024,
        hbuf, b2 + 1024, vT, 1024, 1024, 1024, 8192, 0, 30, 6);

    // scores = h @ G + gb -> attn fp32  [8192,2048] K=1024  (BN=256, mt=32, nbx=8)
    gemm256<256, 1, 0, 0><<<g256, b512, 131072, stream>>>(hbuf, GT, gbuf, attn,
        1024, 1024, 1024, 2048, 0, 30, 3);

    // masked softmax in-place (fp32) + bf16 copy -> abf (GT/gbuf dead after scores)
    softmax_rows_f32<<<dim3(8192), blk, 0, stream>>>(attn, abf, mask, Lr);

    // output = attn @ v, batched over 4 via B-pointer into vT
    //   BT = vT + bz*2048, ldb 8192  [8192,1024] K=2048  (BN=128, mt=32, nbx=8)
    gemm256<128, 1, 0, 0><<<g256, b512, 98304, stream>>>(abf, vT, nullptr, outp,
        2048, 2048, 8192, 1024, 2048, 3, 3);
}

// Round 7
// 335.232 us; speedup vs baseline: 1.0803x; 1.0803x over previous
//
#include <hip/hip_runtime.h>
#include <cstdint>
#include <cstddef>

// ---------- bf16 helpers (bit-level) ----------
__device__ __forceinline__ uint16_t f2bf(float f) {
    union { float f; uint32_t i; } w; w.f = f;
    uint32_t x = w.i;
    uint32_t r = (x + 0x7FFFu + ((x >> 16) & 1u)) >> 16;   // RNE
    return (uint16_t)r;
}

typedef __bf16 bf16x8 __attribute__((ext_vector_type(8)));
typedef float  f32x4  __attribute__((ext_vector_type(4)));

// async global->LDS, 16B per lane; LDS dest is wave-uniform base + lane*16
__device__ __forceinline__ void load_lds16(const void* gptr, void* lptr) {
    __builtin_amdgcn_global_load_lds(
        (__attribute__((address_space(1))) void*)gptr,
        (__attribute__((address_space(3))) void*)lptr,
        16, 0, 0);
}

// ---------- 256xBN phased GEMM engine (frozen at R2 form) ----------
// C[M,N] = act(A[M,K] @ BT[N,K]^T + bias); A,BT bf16; BK=64 as 2 kh-subtiles.
// ENGINE STATUS (R0-R5): ~570-600 TF at these shapes. Schedule micro-fixes
// (lgkmcnt pin R2, sched_barrier pins R3: -7.7us) don't move it — matches
// learn_hip m232 (8-phase port null, "needs derived-waits port"). FROZEN.
// R5 lesson: algebra that trades GEMM FLOPs for small helper kernels LOSES
// (+34us) — grid-starved helpers (8-block GEMV ≈ 20-40us) dwarf the savings.
// Grid is ALWAYS 256 blocks (1/CU): mtiles * nbx == 256, nbx = 1<<nbxShift.
// XCD swizzle: q = (g&7)*32 + (g>>3); by = q>>nbxShift (M-tile), bx = rest.
// Batch on B only: bz = by >> byShift.
// VSPLIT (kv GEMM): cols <1024 -> Cv (k, row-major, ldc); cols >=1024 ->
// C2 TRANSPOSED (vT[d][l_global], ld 8192). Block-uniform branch (gn0 % 256
// == 0). Kills the separate 64MB transpose pass; L2 write-back assembles the
// scattered 2B stores (each block fully covers a 256x256 vT subtile).
template<int BN, int OUTFP32, int RELU, int VSPLIT>
__global__ __launch_bounds__(512, 2)
void gemm256(const uint16_t* __restrict__ A, const uint16_t* __restrict__ BT,
             const float* __restrict__ bias, void* __restrict__ Cv,
             uint16_t* __restrict__ C2,
             int K, int lda, int ldb, int ldc,
             long long sB, int byShift, int nbxShift)
{
    extern __shared__ uint16_t lds[];
    constexpr int SB  = (BN == 256) ? 2 : 1;  // B gload_lds insts per kh
    constexpr int WN  = BN / 64;              // waves along N (4 or 2)
    constexpr int MI  = 2 * WN;               // frag-rows per wave (8 or 4)
    constexpr int SBE = BN * 32;              // B subtile elems

    const int g   = (int)blockIdx.x + (int)gridDim.x * (int)blockIdx.y;
    const int xcd = g & 7, ii = g >> 3;
    const int q   = xcd * 32 + ii;            // 0..255
    const int by  = q >> nbxShift;
    const int bx  = q & ((1 << nbxShift) - 1);
    const int gm0 = by * 256, gn0 = bx * BN;
    const int bz  = by >> byShift;
    BT += (long long)bz * sB;

    const int t    = threadIdx.x;
    const int w    = t >> 6, lane = t & 63;
    const int l15  = lane & 15, quad = lane >> 4;
    const int wr   = w / WN, wc = w % WN;

    // frag-read swizzle + row bases
    const int cpr  = quad ^ ((l15 >> 1) & 3);
    const int arow = wr * (32 * WN) + l15;    // + (mh*64) + i*16
    const int brow = wc * 64 + l15;           // + ni*16

    // staging map: thread t covers row r0 = t>>2 (0..127), 16B chunk qg of that
    // row, where qg = (t&3) ^ ((r0>>1)&3).
    const int r0 = t >> 2;
    const int qg = (t & 3) ^ ((t >> 3) & 3);
    const uint16_t* aS0 = A  + (size_t)(gm0 + r0) * lda + qg * 8;
    const uint16_t* aS1 = aS0 + (size_t)128 * lda;
    const uint16_t* bS0 = BT + (size_t)(gn0 + r0) * ldb + qg * 8;
    const uint16_t* bS1 = bS0 + (size_t)128 * ldb;   // deref'd only if BN==256
    const int ldw = w * 512;                  // per-wave LDS elem offset

#define SUBA(nb, kh) (lds + ((nb) * 2 + (kh)) * 8192)
#define SUBB(nb, kh) (lds + 32768 + ((nb) * 2 + (kh)) * SBE)
#define STAGE_A(nb, kh, k0s) do {                                               \
        load_lds16(aS0 + (k0s) + (kh) * 32, (void*)(SUBA(nb, kh) + ldw));       \
        load_lds16(aS1 + (k0s) + (kh) * 32, (void*)(SUBA(nb, kh) + 4096 + ldw));\
    } while (0)
#define STAGE_B(nb, kh, k0s) do {                                               \
        load_lds16(bS0 + (k0s) + (kh) * 32, (void*)(SUBB(nb, kh) + ldw));       \
        if constexpr (BN == 256)                                                \
            load_lds16(bS1 + (k0s) + (kh) * 32,                                 \
                       (void*)(SUBB(nb, kh) + 4096 + ldw));                     \
    } while (0)
#define VMW do {                                                                \
        if constexpr (SB == 2) asm volatile("s_waitcnt vmcnt(4)" ::: "memory"); \
        else                   asm volatile("s_waitcnt vmcnt(3)" ::: "memory"); \
    } while (0)
#define LGKM0 asm volatile("s_waitcnt lgkmcnt(0)" ::: "memory")
#define NOWAIT ((void)0)

    f32x4 acc[MI][4] = {};
    bf16x8 bF[4];

    // prologue: stage tile 0 fully; wait until (Ak0,Bk0) landed
    STAGE_A(0, 0, 0); STAGE_B(0, 0, 0); STAGE_A(0, 1, 0); STAGE_B(0, 1, 0);
    VMW;
    __builtin_amdgcn_s_barrier();

    const int NT = K >> 6;
    for (int kt = 0; kt < NT; ++kt) {
        const int buf = kt & 1, nb = buf ^ 1;
        const int nk0 = (kt + 1 < NT) ? ((kt + 1) << 6) : 0;   // wrap: dead stage

        if constexpr (BN == 256) {
#define PHASE256(kh, mh, STAGE_STMT, VM_STMT)                                       \
            {                                                                       \
                const uint16_t* As_ = SUBA(buf, kh);                                \
                const uint16_t* Bs_ = SUBB(buf, kh);                                \
                bf16x8 aF[4];                                                       \
                _Pragma("unroll")                                                   \
                for (int i = 0; i < 4; i++)                                         \
                    aF[i] = *(const bf16x8*)(As_ + (arow + (mh) * 64 + i * 16) * 32 + cpr * 8); \
                if ((mh) == 0) {                                                    \
                    _Pragma("unroll")                                               \
                    for (int ni = 0; ni < 4; ni++)                                  \
                        bF[ni] = *(const bf16x8*)(Bs_ + (brow + ni * 16) * 32 + cpr * 8); \
                }                                                                   \
                STAGE_STMT;                                                         \
                __builtin_amdgcn_s_barrier();                                       \
                LGKM0;                                                              \
                __builtin_amdgcn_s_setprio(1);                                      \
                _Pragma("unroll")                                                   \
                for (int i = 0; i < 4; i++)                                         \
                    _Pragma("unroll")                                               \
                    for (int ni = 0; ni < 4; ni++)                                  \
                        acc[(mh) * 4 + i][ni] = __builtin_amdgcn_mfma_f32_16x16x32_bf16( \
                            aF[i], bF[ni], acc[(mh) * 4 + i][ni], 0, 0, 0);         \
                __builtin_amdgcn_s_setprio(0);                                      \
                VM_STMT;                                                            \
                __builtin_amdgcn_s_barrier();                                       \
            }
            PHASE256(0, 0, STAGE_A(nb, 0, nk0), NOWAIT)
            PHASE256(0, 1, STAGE_B(nb, 0, nk0), VMW)
            PHASE256(1, 0, STAGE_A(nb, 1, nk0), NOWAIT)
            PHASE256(1, 1, STAGE_B(nb, 1, nk0), VMW)
#undef PHASE256
        } else {
#define PHASE128(kh)                                                                \
            {                                                                       \
                const uint16_t* As_ = SUBA(buf, kh);                                \
                const uint16_t* Bs_ = SUBB(buf, kh);                                \
                bf16x8 aF[4], bG[4];                                                \
                _Pragma("unroll")                                                   \
                for (int i = 0; i < 4; i++)                                         \
                    aF[i] = *(const bf16x8*)(As_ + (arow + i * 16) * 32 + cpr * 8); \
                _Pragma("unroll")                                                   \
                for (int ni = 0; ni < 4; ni++)                                      \
                    bG[ni] = *(const bf16x8*)(Bs_ + (brow + ni * 16) * 32 + cpr * 8); \
                STAGE_A(nb, kh, nk0);                                               \
                STAGE_B(nb, kh, nk0);                                               \
                __builtin_amdgcn_s_barrier();                                       \
                LGKM0;                                                              \
                __builtin_amdgcn_s_setprio(1);                                      \
                _Pragma("unroll")                                                   \
                for (int i = 0; i < 4; i++)                                         \
                    _Pragma("unroll")                                               \
                    for (int ni = 0; ni < 4; ni++)                                  \
                        acc[i][ni] = __builtin_amdgcn_mfma_f32_16x16x32_bf16(       \
                            aF[i], bG[ni], acc[i][ni], 0, 0, 0);                    \
                __builtin_amdgcn_s_setprio(0);                                      \
                VMW;                                                                \
                __builtin_amdgcn_s_barrier();                                       \
            }
            PHASE128(0)
            PHASE128(1)
#undef PHASE128
        }
    }
    asm volatile("s_waitcnt vmcnt(0)" ::: "memory");   // drain dead stage

    // epilogue: C/D layout col=lane&15, row=quad*4+reg
#pragma unroll
    for (int ni = 0; ni < 4; ni++) {
        const int gcol = gn0 + wc * 64 + ni * 16 + l15;
        const float bv = bias ? bias[gcol] : 0.0f;
#pragma unroll
        for (int mi = 0; mi < MI; mi++) {
#pragma unroll
            for (int r = 0; r < 4; r++) {
                const int grow = gm0 + wr * (32 * WN) + mi * 16 + quad * 4 + r;
                float v = acc[mi][ni][r] + bv;
                if (RELU) v = fmaxf(v, 0.0f);
                if (VSPLIT) {
                    // k-half row-major; v-half direct-transposed into vT
                    if (gcol < 1024)
                        ((uint16_t*)Cv)[(size_t)grow * ldc + gcol] = f2bf(v);
                    else
                        C2[(size_t)(gcol - 1024) * 8192 + grow] = f2bf(v);
                } else if (OUTFP32) {
                    ((float*)Cv)[(size_t)grow * ldc + gcol] = v;
                } else {
                    ((uint16_t*)Cv)[(size_t)grow * ldc + gcol] = f2bf(v);
                }
            }
        }
    }
#undef SUBA
#undef SUBB
#undef STAGE_A
#undef STAGE_B
#undef VMW
#undef LGKM0
#undef NOWAIT
}

// ---------- elementwise cast fp32 -> bf16 (8 elems/thread) ----------
__global__ __launch_bounds__(256)
void cast_f32_bf16(const float* __restrict__ src, uint16_t* __restrict__ dst)
{
    const size_t i = ((size_t)blockIdx.x * 256 + threadIdx.x) * 8;
    float4 a = *(const float4*)(src + i);
    float4 b = *(const float4*)(src + i + 4);
    union { __bf16 h[8]; uint4 q; } u;
    u.h[0] = (__bf16)a.x; u.h[1] = (__bf16)a.y;
    u.h[2] = (__bf16)a.z; u.h[3] = (__bf16)a.w;
    u.h[4] = (__bf16)b.x; u.h[5] = (__bf16)b.y;
    u.h[6] = (__bf16)b.z; u.h[7] = (__bf16)b.w;
    *(uint4*)(dst + i) = u.q;
}

// ---------- transpose fp32 -> bf16: dst[n][k] = bf16(src[k][n]) ----------
__global__ __launch_bounds__(256)
void transpose_f32_to_bf16(const float* __restrict__ src, uint16_t* __restrict__ dst,
                           int src_ld, int dst_ld)
{
    __shared__ uint16_t tile[64 * 65];
    const int k0 = blockIdx.y * 64, n0 = blockIdx.x * 64;
    const int t = threadIdx.x;
#pragma unroll
    for (int i = 0; i < 16; i++) {
        int idx = i * 256 + t;
        int r = idx >> 6, c = idx & 63;
        tile[c * 65 + r] = f2bf(src[(size_t)(k0 + r) * src_ld + n0 + c]);
    }
    __syncthreads();
#pragma unroll
    for (int i = 0; i < 16; i++) {
        int idx = i * 256 + t;
        int n = idx >> 6, k = idx & 63;
        dst[(size_t)(n0 + n) * dst_ld + k0 + k] = tile[n * 65 + k];
    }
}

// ---------- in-place masked softmax, fp32; also emits bf16 copy ----------
__global__ __launch_bounds__(256)
void softmax_rows_f32(float* __restrict__ S, uint16_t* __restrict__ Sbf,
                      const int* __restrict__ mask, int L)
{
    const int row = blockIdx.x;
    const int b = row >> 11;                 // L == 2048
    float* rp = S + (size_t)row * L;
    uint16_t* bp = Sbf + (size_t)row * L;
    const int* mrow = mask + (size_t)b * L;
    const int t = threadIdx.x;
    const int c0 = t * 8;

    float v[8];
    *(float4*)(v + 0) = *(const float4*)(rp + c0);
    *(float4*)(v + 4) = *(const float4*)(rp + c0 + 4);
    bool mk[8];
    float lmax = -1e30f;
#pragma unroll
    for (int j = 0; j < 8; j++) {
        mk[j] = (mrow[c0 + j] != 0);
        if (mk[j]) lmax = fmaxf(lmax, v[j]);
    }
#pragma unroll
    for (int off = 32; off > 0; off >>= 1)
        lmax = fmaxf(lmax, __shfl_xor(lmax, off, 64));

    __shared__ float redm[4];
    __shared__ float reds[4];
    const int w = t >> 6, lane = t & 63;
    if (lane == 0) redm[w] = lmax;
    __syncthreads();
    lmax = fmaxf(fmaxf(redm[0], redm[1]), fmaxf(redm[2], redm[3]));

    float e[8];
    float lsum = 0.f;
#pragma unroll
    for (int j = 0; j < 8; j++) {
        e[j] = mk[j] ? __expf(v[j] - lmax) : 0.0f;
        lsum += e[j];
    }
#pragma unroll
    for (int off = 32; off > 0; off >>= 1)
        lsum += __shfl_xor(lsum, off, 64);
    if (lane == 0) reds[w] = lsum;
    __syncthreads();
    lsum = reds[0] + reds[1] + reds[2] + reds[3];

    const float inv = 1.0f / lsum;
    uint16_t ub[8];
#pragma unroll
    for (int j = 0; j < 8; j++) {
        v[j] = e[j] * inv;
        ub[j] = f2bf(v[j]);
    }
    *(float4*)(rp + c0)     = *(const float4*)(v + 0);
    *(float4*)(rp + c0 + 4) = *(const float4*)(v + 4);
    *(uint4*)(bp + c0)      = *(const uint4*)ub;
}

extern "C" void kernel_launch(void* const* d_in, const int* in_sizes, int n_in,
                              void* d_out, int out_size, void* d_ws, size_t ws_size,
                              hipStream_t stream)
{
    const float* x    = (const float*)d_in[0];  // [4,2048,1024] fp32
    const int*   mask = (const int*)d_in[1];    // [4,1,2048] int32
    const float* W1   = (const float*)d_in[2];  // [1024,1024]
    const float* b1   = (const float*)d_in[3];  // [1024]
    const float* W2   = (const float*)d_in[4];  // [1024,2048]
    const float* b2   = (const float*)d_in[5];  // [2048]
    const float* D2L  = (const float*)d_in[6];  // [1024,4096]

    const int Lr = 2048, D = 1024, M = 4 * Lr;  // M = 8192
    float* outp = (float*)d_out;                // [8192][1024] fp32
    float* attn = outp + (size_t)M * D;         // [8192][2048] fp32

    // ws layout (bf16 elems), 37M elems = 74MB (R2-proven footprint):
    //  @0    W1T   1M
    //  @1M   W2T   2M   ([2048][1024] = W2^T)
    //  @3M   D2LT  2M   (D2L[:, :2048]^T)
    //  @5M   hbuf  8M   (h; dead after kv GEMM)
    //  @13M  xbf   8M early (x cast; dead after h GEMM) -> kbuf 8M (kv k-half)
    //  @13M..29M  abf 16M late (softmax bf16 out; kbuf dead after scores GEMM)
    //  @29M  vT    8M   ([1024 d][8192 l] bf16, written transposed by kv GEMM)
    uint16_t* W1T  = (uint16_t*)d_ws;
    uint16_t* W2T  = W1T + (size_t)1024 * 1024;
    uint16_t* D2LT = W2T + (size_t)2048 * 1024;
    uint16_t* hbuf = D2LT + (size_t)2048 * 1024;
    uint16_t* xbf  = hbuf + (size_t)M * D;          // @13M
    uint16_t* kbuf = xbf;                           // after h GEMM
    uint16_t* abf  = xbf;                           // after scores GEMM (16M)
    uint16_t* vT   = xbf + (size_t)M * 2048;        // @29M = 13M + 16M

    dim3 blk(256);
    const dim3 g256(8, 32), b512(512);

    // opt-in dynamic LDS (host-side attr set; graph-capture-safe)
    hipFuncSetAttribute(reinterpret_cast<const void*>(&gemm256<128, 0, 1, 0>),
                        hipFuncAttributeMaxDynamicSharedMemorySize, 98304);
    hipFuncSetAttribute(reinterpret_cast<const void*>(&gemm256<256, 0, 0, 1>),
                        hipFuncAttributeMaxDynamicSharedMemorySize, 131072);
    hipFuncSetAttribute(reinterpret_cast<const void*>(&gemm256<256, 1, 0, 0>),
                        hipFuncAttributeMaxDynamicSharedMemorySize, 131072);
    hipFuncSetAttribute(reinterpret_cast<const void*>(&gemm256<128, 1, 0, 0>),
                        hipFuncAttributeMaxDynamicSharedMemorySize, 98304);

    // casts / transposes of inputs
    cast_f32_bf16<<<dim3(4096), blk, 0, stream>>>(x, xbf);
    transpose_f32_to_bf16<<<dim3(16, 16), blk, 0, stream>>>(W1,  W1T,  1024, 1024);
    transpose_f32_to_bf16<<<dim3(32, 16), blk, 0, stream>>>(W2,  W2T,  2048, 1024);
    transpose_f32_to_bf16<<<dim3(32, 16), blk, 0, stream>>>(D2L, D2LT, 4096, 1024);

    // h = relu(x @ W1 + b1)   [8192,1024] K=1024  (BN=128, mt=32, nbx=8)
    gemm256<128, 0, 1, 0><<<g256, b512, 98304, stream>>>(xbf, W1T, b1, hbuf, nullptr,
        1024, 1024, 1024, 1024, 0, 30, 3);

    // kv = h @ W2 + b2  [8192,2048] K=1024  (BN=256, mt=32, nbx=8), VSPLIT:
    //   k-half -> kbuf [8192][1024]; v-half -> vT [1024][8192] (transposed)
    gemm256<256, 0, 0, 1><<<g256, b512, 131072, stream>>>(hbuf, W2T, b2, kbuf, vT,
        1024, 1024, 1024, 1024, 0, 30, 3);

    // scores = k @ D_to_L[:, :2048] -> attn fp32  [8192,2048] K=1024  (BN=256)
    gemm256<256, 1, 0, 0><<<g256, b512, 131072, stream>>>(kbuf, D2LT, nullptr, attn,
        nullptr, 1024, 1024, 1024, 2048, 0, 30, 3);

    // masked softmax in-place (fp32) + bf16 copy -> abf (kbuf dead now)
    softmax_rows_f32<<<dim3(8192), blk, 0, stream>>>(attn, abf, mask, Lr);

    // output = attn @ v, batched over 4 via B-pointer into vT
    //   BT = vT + bz*2048, ldb 8192  [8192,1024] K=2048  (BN=128, mt=32, nbx=8)
    gemm256<128, 1, 0, 0><<<g256, b512, 98304, stream>>>(abf, vT, nullptr, outp,
        nullptr, 2048, 2048, 8192, 1024, 2048, 3, 3);
}

// Round 8
// 332.745 us; speedup vs baseline: 1.0884x; 1.0075x over previous
//
#include <hip/hip_runtime.h>
#include <cstdint>
#include <cstddef>

// ---------- bf16 helpers (bit-level) ----------
__device__ __forceinline__ uint16_t f2bf(float f) {
    union { float f; uint32_t i; } w; w.f = f;
    uint32_t x = w.i;
    uint32_t r = (x + 0x7FFFu + ((x >> 16) & 1u)) >> 16;   // RNE
    return (uint16_t)r;
}

typedef __bf16 bf16x8 __attribute__((ext_vector_type(8)));
typedef float  f32x4  __attribute__((ext_vector_type(4)));

// async global->LDS, 16B per lane; LDS dest is wave-uniform base + lane*16
__device__ __forceinline__ void load_lds16(const void* gptr, void* lptr) {
    __builtin_amdgcn_global_load_lds(
        (__attribute__((address_space(1))) void*)gptr,
        (__attribute__((address_space(3))) void*)lptr,
        16, 0, 0);
}

// ---------- 256xBN phased GEMM engine ----------
// R8 = EXACT R2 source (session best, 328.4us) minus the LGKM0 inline-asm.
// A/B rationale (R7 post-mortem): scores GEMM measured 76us/452TF/MfmaUtil 17%
// on the R7 engine vs 60us/573TF on legacy. R1 (this exact phase form, no
// LGKM0) had the gemm256 pair at <=114us combined. Suspects for the
// degradation: (a) LGKM0 forces ALL ds_reads done before ANY MFMA, defeating
// the compiler's fine-grained lgkmcnt(4/3/1/0) interleave; (b) R5's swizzle
// refactor made B-panels cold-stream (HBM ~900cyc > 3-phase prefetch lead).
// This source restores the R2 mapping (B-panel-hot) and drops LGKM0 — one
// variable vs the 328.4 baseline.
// C[M,N] = act(A[M,K] @ BT[N,K]^T + bias); A,BT bf16; BK=64 as 2 kh-subtiles.
// BN=256: 8 waves as 2Mx4N, per-wave 128x64, acc[8][4], 4 phases/K-tile.
// BN=128: 8 waves as 4Mx2N, per-wave  64x64, acc[4][4], 2 phases/K-tile.
// LDS: A = 2buf x 2kh x [256][32] @ 0 (64KB); B = 2buf x 2kh x [BN][32] @ 64KB.
// Chunk swizzle (T2): LDS slot (r,q) holds global 16B chunk (q ^ ((r>>1)&3)) of
// row r; gload_lds dest stays linear (m104), source address carries the XOR.
// vmcnt cadence: counted vmcnt(4)/vmcnt(3), never 0 in-loop (T4); 3-4 phase
// prefetch lead per staged half.
// Batch on B only: bz = by >> byShift.
template<int BN, int OUTFP32, int RELU>
__global__ __launch_bounds__(512, 2)
void gemm256(const uint16_t* __restrict__ A, const uint16_t* __restrict__ BT,
             const float* __restrict__ bias, void* __restrict__ Cv,
             int K, int lda, int ldb, int ldc,
             long long sB, int byShift)
{
    extern __shared__ uint16_t lds[];
    constexpr int SB  = (BN == 256) ? 2 : 1;  // B gload_lds insts per kh
    constexpr int WN  = BN / 64;              // waves along N (4 or 2)
    constexpr int MI  = 2 * WN;               // frag-rows per wave (8 or 4)
    constexpr int SBE = BN * 32;              // B subtile elems

    // XCD swizzle (R2 mapping): 256 blocks, xcd = g&7; each XCD owns 4
    // contiguous M-tiles; consecutive ii share the same bx -> B-panel L2 reuse.
    const int g   = (int)blockIdx.x + (int)gridDim.x * (int)blockIdx.y;
    const int xcd = g & 7, ii = g >> 3;
    const int by  = xcd * 4 + (ii & 3);
    const int bx  = ii >> 2;
    const int gm0 = by * 256, gn0 = bx * BN;
    const int bz  = by >> byShift;
    BT += (long long)bz * sB;

    const int t    = threadIdx.x;
    const int w    = t >> 6, lane = t & 63;
    const int l15  = lane & 15, quad = lane >> 4;
    const int wr   = w / WN, wc = w % WN;

    // frag-read swizzle + row bases
    const int cpr  = quad ^ ((l15 >> 1) & 3);
    const int arow = wr * (32 * WN) + l15;    // + (mh*64) + i*16
    const int brow = wc * 64 + l15;           // + ni*16

    // staging map: thread t covers row r0 = t>>2 (0..127), 16B chunk qg of that
    // row, where qg = (t&3) ^ ((r0>>1)&3).
    const int r0 = t >> 2;
    const int qg = (t & 3) ^ ((t >> 3) & 3);
    const uint16_t* aS0 = A  + (size_t)(gm0 + r0) * lda + qg * 8;
    const uint16_t* aS1 = aS0 + (size_t)128 * lda;
    const uint16_t* bS0 = BT + (size_t)(gn0 + r0) * ldb + qg * 8;
    const uint16_t* bS1 = bS0 + (size_t)128 * ldb;   // deref'd only if BN==256
    const int ldw = w * 512;                  // per-wave LDS elem offset

#define SUBA(nb, kh) (lds + ((nb) * 2 + (kh)) * 8192)
#define SUBB(nb, kh) (lds + 32768 + ((nb) * 2 + (kh)) * SBE)
#define STAGE_A(nb, kh, k0s) do {                                               \
        load_lds16(aS0 + (k0s) + (kh) * 32, (void*)(SUBA(nb, kh) + ldw));       \
        load_lds16(aS1 + (k0s) + (kh) * 32, (void*)(SUBA(nb, kh) + 4096 + ldw));\
    } while (0)
#define STAGE_B(nb, kh, k0s) do {                                               \
        load_lds16(bS0 + (k0s) + (kh) * 32, (void*)(SUBB(nb, kh) + ldw));       \
        if constexpr (BN == 256)                                                \
            load_lds16(bS1 + (k0s) + (kh) * 32,                                 \
                       (void*)(SUBB(nb, kh) + 4096 + ldw));                     \
    } while (0)
#define VMW do {                                                                \
        if constexpr (SB == 2) asm volatile("s_waitcnt vmcnt(4)" ::: "memory"); \
        else                   asm volatile("s_waitcnt vmcnt(3)" ::: "memory"); \
    } while (0)
#define NOWAIT ((void)0)

    f32x4 acc[MI][4] = {};
    bf16x8 bF[4];

    // prologue: stage tile 0 fully; wait until (Ak0,Bk0) landed
    STAGE_A(0, 0, 0); STAGE_B(0, 0, 0); STAGE_A(0, 1, 0); STAGE_B(0, 1, 0);
    VMW;
    __builtin_amdgcn_s_barrier();

    const int NT = K >> 6;
    for (int kt = 0; kt < NT; ++kt) {
        const int buf = kt & 1, nb = buf ^ 1;
        const int nk0 = (kt + 1 < NT) ? ((kt + 1) << 6) : 0;   // wrap: dead stage

        if constexpr (BN == 256) {
            // 4 phases: (kh, mh); bF persists across the mh pair.
#define PHASE256(kh, mh, STAGE_STMT, VM_STMT)                                       \
            {                                                                       \
                const uint16_t* As_ = SUBA(buf, kh);                                \
                const uint16_t* Bs_ = SUBB(buf, kh);                                \
                bf16x8 aF[4];                                                       \
                _Pragma("unroll")                                                   \
                for (int i = 0; i < 4; i++)                                         \
                    aF[i] = *(const bf16x8*)(As_ + (arow + (mh) * 64 + i * 16) * 32 + cpr * 8); \
                if ((mh) == 0) {                                                    \
                    _Pragma("unroll")                                               \
                    for (int ni = 0; ni < 4; ni++)                                  \
                        bF[ni] = *(const bf16x8*)(Bs_ + (brow + ni * 16) * 32 + cpr * 8); \
                }                                                                   \
                STAGE_STMT;                                                         \
                __builtin_amdgcn_s_barrier();                                       \
                __builtin_amdgcn_s_setprio(1);                                      \
                _Pragma("unroll")                                                   \
                for (int i = 0; i < 4; i++)                                         \
                    _Pragma("unroll")                                               \
                    for (int ni = 0; ni < 4; ni++)                                  \
                        acc[(mh) * 4 + i][ni] = __builtin_amdgcn_mfma_f32_16x16x32_bf16( \
                            aF[i], bF[ni], acc[(mh) * 4 + i][ni], 0, 0, 0);         \
                __builtin_amdgcn_s_setprio(0);                                      \
                VM_STMT;                                                            \
                __builtin_amdgcn_s_barrier();                                       \
            }
            PHASE256(0, 0, STAGE_A(nb, 0, nk0), NOWAIT)
            PHASE256(0, 1, STAGE_B(nb, 0, nk0), VMW)
            PHASE256(1, 0, STAGE_A(nb, 1, nk0), NOWAIT)
            PHASE256(1, 1, STAGE_B(nb, 1, nk0), VMW)
#undef PHASE256
        } else {
            // 2 phases: (kh); 16 MFMA per phase (all 4 mi x 4 ni).
#define PHASE128(kh)                                                                \
            {                                                                       \
                const uint16_t* As_ = SUBA(buf, kh);                                \
                const uint16_t* Bs_ = SUBB(buf, kh);                                \
                bf16x8 aF[4], bG[4];                                                \
                _Pragma("unroll")                                                   \
                for (int i = 0; i < 4; i++)                                         \
                    aF[i] = *(const bf16x8*)(As_ + (arow + i * 16) * 32 + cpr * 8); \
                _Pragma("unroll")                                                   \
                for (int ni = 0; ni < 4; ni++)                                      \
                    bG[ni] = *(const bf16x8*)(Bs_ + (brow + ni * 16) * 32 + cpr * 8); \
                STAGE_A(nb, kh, nk0);                                               \
                STAGE_B(nb, kh, nk0);                                               \
                __builtin_amdgcn_s_barrier();                                       \
                __builtin_amdgcn_s_setprio(1);                                      \
                _Pragma("unroll")                                                   \
                for (int i = 0; i < 4; i++)                                         \
                    _Pragma("unroll")                                               \
                    for (int ni = 0; ni < 4; ni++)                                  \
                        acc[i][ni] = __builtin_amdgcn_mfma_f32_16x16x32_bf16(       \
                            aF[i], bG[ni], acc[i][ni], 0, 0, 0);                    \
                __builtin_amdgcn_s_setprio(0);                                      \
                VMW;                                                                \
                __builtin_amdgcn_s_barrier();                                       \
            }
            PHASE128(0)
            PHASE128(1)
#undef PHASE128
        }
    }
    asm volatile("s_waitcnt vmcnt(0)" ::: "memory");   // drain dead stage

    // epilogue: C/D layout col=lane&15, row=quad*4+reg
#pragma unroll
    for (int ni = 0; ni < 4; ni++) {
        const int gcol = gn0 + wc * 64 + ni * 16 + l15;
        const float bv = bias ? bias[gcol] : 0.0f;
#pragma unroll
        for (int mi = 0; mi < MI; mi++) {
#pragma unroll
            for (int r = 0; r < 4; r++) {
                const int grow = gm0 + wr * (32 * WN) + mi * 16 + quad * 4 + r;
                float v = acc[mi][ni][r] + bv;
                if (RELU) v = fmaxf(v, 0.0f);
                if (OUTFP32) ((float*)Cv)[(size_t)grow * ldc + gcol] = v;
                else         ((uint16_t*)Cv)[(size_t)grow * ldc + gcol] = f2bf(v);
            }
        }
    }
#undef SUBA
#undef SUBB
#undef STAGE_A
#undef STAGE_B
#undef VMW
#undef NOWAIT
}

// ---------- elementwise cast fp32 -> bf16 (8 elems/thread) ----------
__global__ __launch_bounds__(256)
void cast_f32_bf16(const float* __restrict__ src, uint16_t* __restrict__ dst)
{
    const size_t i = ((size_t)blockIdx.x * 256 + threadIdx.x) * 8;
    float4 a = *(const float4*)(src + i);
    float4 b = *(const float4*)(src + i + 4);
    union { __bf16 h[8]; uint4 q; } u;
    u.h[0] = (__bf16)a.x; u.h[1] = (__bf16)a.y;
    u.h[2] = (__bf16)a.z; u.h[3] = (__bf16)a.w;
    u.h[4] = (__bf16)b.x; u.h[5] = (__bf16)b.y;
    u.h[6] = (__bf16)b.z; u.h[7] = (__bf16)b.w;
    *(uint4*)(dst + i) = u.q;
}

// ---------- transpose fp32 -> bf16: dst[n][k] = bf16(src[k][n]) ----------
__global__ __launch_bounds__(256)
void transpose_f32_to_bf16(const float* __restrict__ src, uint16_t* __restrict__ dst,
                           int src_ld, int dst_ld)
{
    __shared__ uint16_t tile[64 * 65];
    const int k0 = blockIdx.y * 64, n0 = blockIdx.x * 64;
    const int t = threadIdx.x;
#pragma unroll
    for (int i = 0; i < 16; i++) {
        int idx = i * 256 + t;
        int r = idx >> 6, c = idx & 63;
        tile[c * 65 + r] = f2bf(src[(size_t)(k0 + r) * src_ld + n0 + c]);
    }
    __syncthreads();
#pragma unroll
    for (int i = 0; i < 16; i++) {
        int idx = i * 256 + t;
        int n = idx >> 6, k = idx & 63;
        dst[(size_t)(n0 + n) * dst_ld + k0 + k] = tile[n * 65 + k];
    }
}

// ---------- transpose bf16 -> bf16 (batched) ----------
__global__ __launch_bounds__(256)
void transpose_bf16(const uint16_t* __restrict__ src, uint16_t* __restrict__ dst,
                    int src_ld, int dst_ld, long long sS, long long sD)
{
    __shared__ uint16_t tile[64 * 65];
    src += (long long)blockIdx.z * sS;
    dst += (long long)blockIdx.z * sD;
    const int k0 = blockIdx.y * 64, n0 = blockIdx.x * 64;
    const int t = threadIdx.x;
#pragma unroll
    for (int i = 0; i < 16; i++) {
        int idx = i * 256 + t;
        int r = idx >> 6, c = idx & 63;
        tile[c * 65 + r] = src[(size_t)(k0 + r) * src_ld + n0 + c];
    }
    __syncthreads();
#pragma unroll
    for (int i = 0; i < 16; i++) {
        int idx = i * 256 + t;
        int n = idx >> 6, k = idx & 63;
        dst[(size_t)(n0 + n) * dst_ld + k0 + k] = tile[n * 65 + k];
    }
}

// ---------- in-place masked softmax, fp32; also emits bf16 copy ----------
__global__ __launch_bounds__(256)
void softmax_rows_f32(float* __restrict__ S, uint16_t* __restrict__ Sbf,
                      const int* __restrict__ mask, int L)
{
    const int row = blockIdx.x;
    const int b = row >> 11;                 // L == 2048
    float* rp = S + (size_t)row * L;
    uint16_t* bp = Sbf + (size_t)row * L;
    const int* mrow = mask + (size_t)b * L;
    const int t = threadIdx.x;
    const int c0 = t * 8;

    float v[8];
    *(float4*)(v + 0) = *(const float4*)(rp + c0);
    *(float4*)(v + 4) = *(const float4*)(rp + c0 + 4);
    bool mk[8];
    float lmax = -1e30f;
#pragma unroll
    for (int j = 0; j < 8; j++) {
        mk[j] = (mrow[c0 + j] != 0);
        if (mk[j]) lmax = fmaxf(lmax, v[j]);
    }
#pragma unroll
    for (int off = 32; off > 0; off >>= 1)
        lmax = fmaxf(lmax, __shfl_xor(lmax, off, 64));

    __shared__ float redm[4];
    __shared__ float reds[4];
    const int w = t >> 6, lane = t & 63;
    if (lane == 0) redm[w] = lmax;
    __syncthreads();
    lmax = fmaxf(fmaxf(redm[0], redm[1]), fmaxf(redm[2], redm[3]));

    float e[8];
    float lsum = 0.f;
#pragma unroll
    for (int j = 0; j < 8; j++) {
        e[j] = mk[j] ? __expf(v[j] - lmax) : 0.0f;
        lsum += e[j];
    }
#pragma unroll
    for (int off = 32; off > 0; off >>= 1)
        lsum += __shfl_xor(lsum, off, 64);
    if (lane == 0) reds[w] = lsum;
    __syncthreads();
    lsum = reds[0] + reds[1] + reds[2] + reds[3];

    const float inv = 1.0f / lsum;
    uint16_t ub[8];
#pragma unroll
    for (int j = 0; j < 8; j++) {
        v[j] = e[j] * inv;
        ub[j] = f2bf(v[j]);
    }
    *(float4*)(rp + c0)     = *(const float4*)(v + 0);
    *(float4*)(rp + c0 + 4) = *(const float4*)(v + 4);
    *(uint4*)(bp + c0)      = *(const uint4*)ub;
}

extern "C" void kernel_launch(void* const* d_in, const int* in_sizes, int n_in,
                              void* d_out, int out_size, void* d_ws, size_t ws_size,
                              hipStream_t stream)
{
    const float* x    = (const float*)d_in[0];  // [4,2048,1024] fp32
    const int*   mask = (const int*)d_in[1];    // [4,1,2048] int32
    const float* W1   = (const float*)d_in[2];  // [1024,1024]
    const float* b1   = (const float*)d_in[3];  // [1024]
    const float* W2   = (const float*)d_in[4];  // [1024,2048]
    const float* b2   = (const float*)d_in[5];  // [2048]
    const float* D2L  = (const float*)d_in[6];  // [1024,4096]

    const int Lr = 2048, D = 1024, M = 4 * Lr;  // M = 8192
    float* outp = (float*)d_out;                // [8192][1024] fp32
    float* attn = outp + (size_t)M * D;         // [8192][2048] fp32

    // ws layout (bf16 elems): W1T | W2T | D2LT | h(->vT) | kv(->attn_bf16) | xbf
    uint16_t* W1T  = (uint16_t*)d_ws;                   // 1024*1024
    uint16_t* W2T  = W1T + 1024 * 1024;                 // 2048*1024
    uint16_t* D2LT = W2T + 2048 * 1024;                 // 2048*1024
    uint16_t* hbuf = D2LT + 2048 * 1024;                // 8192*1024
    uint16_t* kv   = hbuf + (size_t)M * D;              // 8192*2048
    uint16_t* xbf  = kv + (size_t)M * 2048;             // 8192*1024
    uint16_t* vT   = hbuf;   // reuse h region after kv GEMM
    uint16_t* abf  = kv;     // reuse kv region after scores GEMM

    dim3 blk(256);
    const dim3 g256(8, 32), b512(512);

    // opt-in to the dynamic LDS sizes (host-side attr set; graph-capture-safe)
    hipFuncSetAttribute(reinterpret_cast<const void*>(&gemm256<256, 0, 0>),
                        hipFuncAttributeMaxDynamicSharedMemorySize, 131072);
    hipFuncSetAttribute(reinterpret_cast<const void*>(&gemm256<256, 1, 0>),
                        hipFuncAttributeMaxDynamicSharedMemorySize, 131072);
    hipFuncSetAttribute(reinterpret_cast<const void*>(&gemm256<128, 0, 1>),
                        hipFuncAttributeMaxDynamicSharedMemorySize, 98304);
    hipFuncSetAttribute(reinterpret_cast<const void*>(&gemm256<128, 1, 0>),
                        hipFuncAttributeMaxDynamicSharedMemorySize, 98304);

    // x -> bf16 (8192*1024 elems, 8/thread)
    cast_f32_bf16<<<dim3(4096), blk, 0, stream>>>(x, xbf);

    // weight cast+transpose -> bf16 [N][K]
    transpose_f32_to_bf16<<<dim3(16, 16), blk, 0, stream>>>(W1,  W1T,  1024, 1024);
    transpose_f32_to_bf16<<<dim3(32, 16), blk, 0, stream>>>(W2,  W2T,  2048, 1024);
    transpose_f32_to_bf16<<<dim3(32, 16), blk, 0, stream>>>(D2L, D2LT, 4096, 1024);

    // h = relu(x @ W1 + b1)   [8192,1024] K=1024  (BN=128 engine)
    gemm256<128, 0, 1><<<g256, b512, 98304, stream>>>(xbf, W1T, b1, hbuf,
        1024, 1024, 1024, 1024, 0, 30);

    // kv = h @ W2 + b2        [8192,2048] K=1024  (BN=256 engine)
    gemm256<256, 0, 0><<<g256, b512, 131072, stream>>>(hbuf, W2T, b2, kv,
        1024, 1024, 1024, 2048, 0, 30);

    // vT[b] = transpose(kv[b][:,1024:2048]) -> [4][1024][2048] bf16
    transpose_bf16<<<dim3(16, 32, 4), blk, 0, stream>>>(kv + 1024, vT,
        2048, 2048, (long long)2048 * 2048, (long long)1024 * 2048);

    // scores = k @ D_to_L[:, :2048] -> attn fp32, K=1024  (BN=256 engine)
    gemm256<256, 1, 0><<<g256, b512, 131072, stream>>>(kv, D2LT, nullptr, attn,
        1024, 2048, 1024, 2048, 0, 30);

    // masked softmax in-place (fp32) + bf16 copy into dead kv region
    softmax_rows_f32<<<dim3(8192), blk, 0, stream>>>(attn, abf, mask, Lr);

    // output = attn @ v, batched over 4 via B-pointer (A,C rows batch-contiguous)
    // [8192,1024] K=2048  (BN=128 engine)
    gemm256<128, 1, 0><<<g256, b512, 98304, stream>>>(abf, vT, nullptr, outp,
        2048, 2048, 2048, 1024, (long long)1024 * 2048, 3);
}